// Round 18
// baseline (120.963 us; speedup 1.0000x reference)
//
#include <hip/hip_runtime.h>
#include <cmath>

#define HH 32
#define TT 4096
#define BB 512
#define NCH 64          // chunks per chain
#define CL  64          // chunk length (NCH*CL == TT)
#define CW  32          // warmup steps (multiple of 8; t0 stays 0 mod 8)
#define RST 36          // ws floats per (chain,chunk) record (144 B)

typedef float  f4     __attribute__((ext_vector_type(4)));
typedef float  f32x4  __attribute__((ext_vector_type(4)));
typedef short  bf16x8 __attribute__((ext_vector_type(8)));
typedef unsigned int u32x4 __attribute__((ext_vector_type(4)));

constexpr float F_EPS  = 1e-10f;
constexpr float F_MINV = 1e-6f;
constexpr float F_L2E  = 1.44269504088896340736f;   // log2(e)
constexpr float F_LN2  = 0.69314718055994530942f;   // ln(2)
constexpr float TWO_PI = 6.28318530717958647693f;

// ---- pair-combine with ^16/^32 partner (verified r8-r16): same value into
// both operands -> {own, partner} in some order -> sum/max unconditional.
#if __has_builtin(__builtin_amdgcn_permlane16_swap)
__device__ __forceinline__ float psum16(float a) {
    auto rr = __builtin_amdgcn_permlane16_swap(__float_as_uint(a), __float_as_uint(a), false, false);
    return __uint_as_float(rr[0]) + __uint_as_float(rr[1]);
}
__device__ __forceinline__ float pmax16(float a) {
    auto rr = __builtin_amdgcn_permlane16_swap(__float_as_uint(a), __float_as_uint(a), false, false);
    return fmaxf(__uint_as_float(rr[0]), __uint_as_float(rr[1]));
}
#else
__device__ __forceinline__ float psum16(float a) {
    float x, y;
    asm volatile("v_mov_b32 %0, %2\n\tv_mov_b32 %1, %2\n\tv_permlane16_swap_b32 %0, %1"
                 : "=&v"(x), "=&v"(y) : "v"(a));
    return x + y;
}
__device__ __forceinline__ float pmax16(float a) {
    float x, y;
    asm volatile("v_mov_b32 %0, %2\n\tv_mov_b32 %1, %2\n\tv_permlane16_swap_b32 %0, %1"
                 : "=&v"(x), "=&v"(y) : "v"(a));
    return fmaxf(x, y);
}
#endif
#if __has_builtin(__builtin_amdgcn_permlane32_swap)
__device__ __forceinline__ float psum32(float a) {
    auto rr = __builtin_amdgcn_permlane32_swap(__float_as_uint(a), __float_as_uint(a), false, false);
    return __uint_as_float(rr[0]) + __uint_as_float(rr[1]);
}
__device__ __forceinline__ float pmax32(float a) {
    auto rr = __builtin_amdgcn_permlane32_swap(__float_as_uint(a), __float_as_uint(a), false, false);
    return fmaxf(__uint_as_float(rr[0]), __uint_as_float(rr[1]));
}
#else
__device__ __forceinline__ float psum32(float a) {
    float x, y;
    asm volatile("v_mov_b32 %0, %2\n\tv_mov_b32 %1, %2\n\tv_permlane32_swap_b32 %0, %1"
                 : "=&v"(x), "=&v"(y) : "v"(a));
    return x + y;
}
__device__ __forceinline__ float pmax32(float a) {
    float x, y;
    asm volatile("v_mov_b32 %0, %2\n\tv_mov_b32 %1, %2\n\tv_permlane32_swap_b32 %0, %1"
                 : "=&v"(x), "=&v"(y) : "v"(a));
    return fmaxf(x, y);
}
#endif

__device__ __forceinline__ unsigned short f2bf(float f) {   // RNE f32->bf16
    unsigned u = __float_as_uint(f);
    return (unsigned short)((u + 0x7FFFu + ((u >> 16) & 1u)) >> 16);
}
__device__ __forceinline__ unsigned cvtpk(float lo, float hi) {
    unsigned r;
    asm("v_cvt_pk_bf16_f32 %0, %1, %2" : "=v"(r) : "v"(lo), "v"(hi));
    return r;
}

// Per-lane setup (verified r13/r16). Lane l: chain-col c16=l&15, quarter g=l>>4.
// sig[e]=4g+(e&3)+16(e>>2) is both the D-fragment row set AND the B-operand
// k-slots (sigma folded into A' columns) -> D feeds B with zero shuffles.
#define MF_SETUP                                                                \
    __shared__ float sA[HH * HH];                                               \
    const int lane = threadIdx.x;                                               \
    const int c16  = lane & 15;                                                 \
    const int g    = lane >> 4;                                                 \
    if (lane < HH) {                                                            \
        float rw[HH];                                                           \
        _Pragma("unroll")                                                       \
        for (int k = 0; k < HH; ++k) rw[k] = tlog[lane * HH + k];               \
        float m = rw[0];                                                        \
        _Pragma("unroll")                                                       \
        for (int k = 1; k < HH; ++k) m = fmaxf(m, rw[k]);                       \
        float z = 0.f;                                                          \
        _Pragma("unroll")                                                       \
        for (int k = 0; k < HH; ++k) { rw[k] = __expf(rw[k] - m); z += rw[k]; } \
        float rz = 1.f / z;                                                     \
        _Pragma("unroll")                                                       \
        for (int k = 0; k < HH; ++k) sA[lane * HH + k] = fmaf(rw[k], rz, F_EPS);\
    }                                                                           \
    __syncthreads();                                                            \
    int sig[8];                                                                 \
    _Pragma("unroll")                                                           \
    for (int e = 0; e < 8; ++e) sig[e] = 4 * g + (e & 3) + 16 * (e >> 2);       \
    bf16x8 aHi, aLo;                                                            \
    _Pragma("unroll")                                                           \
    for (int e = 0; e < 8; ++e) {                                               \
        aHi[e] = (short)f2bf(sA[sig[e] * HH + c16]);                            \
        aLo[e] = (short)f2bf(sA[sig[e] * HH + 16 + c16]);                       \
    }                                                                           \
    float mean8[8], ec1v[8], ec0v[8];                                           \
    _Pragma("unroll")                                                           \
    for (int e = 0; e < 8; ++e) {                                               \
        const int st = sig[e];                                                  \
        mean8[e] = emean[st];                                                   \
        float var = __expf(elvar[st]) + F_MINV;                                 \
        ec1v[e] = 0.5f * F_L2E / var;                                           \
        ec0v[e] = -0.5f * __logf(TWO_PI * var) * F_L2E;                         \
    }

// One recurrence step at t = TB_+U_ (slot (TB_+U_)&7 == U_&7 since TB_%8==0).
#define MSTEP(U_, TB_, HEAVY_, RENORM_, CLAMP_)                                 \
    {                                                                           \
        const float o_ = obuf[(U_) & 7];                                        \
        float qv_[8], e2_[8];                                                   \
        _Pragma("unroll")                                                       \
        for (int e = 0; e < 8; ++e) {                                           \
            float d_ = o_ - mean8[e];                                           \
            qv_[e] = fmaf(d_ * d_, -ec1v[e], ec0v[e]);                          \
            e2_[e] = __builtin_amdgcn_exp2f(qv_[e]);                            \
        }                                                                       \
        f32x4 S0_ = __builtin_amdgcn_mfma_f32_16x16x32_bf16(aHi, Bf, Zc, 0,0,0);\
        f32x4 S1_ = __builtin_amdgcn_mfma_f32_16x16x32_bf16(aLo, Bf, Zc, 0,0,0);\
        sc[0] = S0_[0] * e2_[0]; sc[1] = S0_[1] * e2_[1];                       \
        sc[2] = S0_[2] * e2_[2]; sc[3] = S0_[3] * e2_[3];                       \
        sc[4] = S1_[0] * e2_[4]; sc[5] = S1_[1] * e2_[5];                       \
        sc[6] = S1_[2] * e2_[6]; sc[7] = S1_[3] * e2_[7];                       \
        if (HEAVY_) {                                                           \
            f32x4 v0_, v1_;                                                     \
            v0_[0] = (off + qv_[0] + __builtin_amdgcn_logf(S0_[0])) * F_LN2;    \
            v0_[1] = (off + qv_[1] + __builtin_amdgcn_logf(S0_[1])) * F_LN2;    \
            v0_[2] = (off + qv_[2] + __builtin_amdgcn_logf(S0_[2])) * F_LN2;    \
            v0_[3] = (off + qv_[3] + __builtin_amdgcn_logf(S0_[3])) * F_LN2;    \
            v1_[0] = (off + qv_[4] + __builtin_amdgcn_logf(S1_[0])) * F_LN2;    \
            v1_[1] = (off + qv_[5] + __builtin_amdgcn_logf(S1_[1])) * F_LN2;    \
            v1_[2] = (off + qv_[6] + __builtin_amdgcn_logf(S1_[2])) * F_LN2;    \
            v1_[3] = (off + qv_[7] + __builtin_amdgcn_logf(S1_[3])) * F_LN2;    \
            __builtin_nontemporal_store(v0_, (f32x4*)(ap + 4 * g));             \
            __builtin_nontemporal_store(v1_, (f32x4*)(ap + 16 + 4 * g));        \
            ap += HH;                                                           \
        }                                                                       \
        if (RENORM_) {                                                          \
            float m_ = fmaxf(fmaxf(fmaxf(sc[0], sc[1]), fmaxf(sc[2], sc[3])),   \
                             fmaxf(fmaxf(sc[4], sc[5]), fmaxf(sc[6], sc[7])));  \
            m_ = pmax32(m_); m_ = pmax16(m_);                                   \
            int ee_; frexpf(m_, &ee_);                                          \
            float s_ = ldexpf(1.0f, -ee_);                                      \
            _Pragma("unroll")                                                   \
            for (int e = 0; e < 8; ++e) sc[e] *= s_;                            \
            off += (float)ee_;                                                  \
        }                                                                       \
        {                                                                       \
            union { u32x4 u; bf16x8 h; } cv_;                                   \
            cv_.u[0] = cvtpk(sc[0], sc[1]); cv_.u[1] = cvtpk(sc[2], sc[3]);     \
            cv_.u[2] = cvtpk(sc[4], sc[5]); cv_.u[3] = cvtpk(sc[6], sc[7]);     \
            Bf = cv_.h;                                                         \
        }                                                                       \
        {                                                                       \
            int tr_ = (TB_) + (U_) + 8;                                         \
            if (CLAMP_) tr_ = (tr_ > TT - 1) ? (TT - 1) : tr_;                  \
            obuf[(U_) & 7] = obl[tr_];                                          \
        }                                                                       \
    }

#define MGROUP8(TB_, HEAVY_, CLAMP_)                                            \
    MSTEP(1, TB_, HEAVY_, false, CLAMP_)                                        \
    MSTEP(2, TB_, HEAVY_, false, CLAMP_)                                        \
    MSTEP(3, TB_, HEAVY_, false, CLAMP_)                                        \
    MSTEP(4, TB_, HEAVY_, false, CLAMP_)                                        \
    MSTEP(5, TB_, HEAVY_, false, CLAMP_)                                        \
    MSTEP(6, TB_, HEAVY_, false, CLAMP_)                                        \
    MSTEP(7, TB_, HEAVY_, false, CLAMP_)                                        \
    MSTEP(8, TB_, HEAVY_, true,  CLAMP_)

#define PACK_SC_TO_BF                                                           \
    { union { u32x4 u; bf16x8 h; } cv_;                                         \
      cv_.u[0] = cvtpk(sc[0], sc[1]); cv_.u[1] = cvtpk(sc[2], sc[3]);           \
      cv_.u[2] = cvtpk(sc[4], sc[5]); cv_.u[3] = cvtpk(sc[6], sc[7]);           \
      Bf = cv_.h; }

#define CHAIN_SUM(V_)                                                           \
    float V_ = ((sc[0] + sc[1]) + (sc[2] + sc[3]))                              \
             + ((sc[4] + sc[5]) + (sc[6] + sc[7]));                             \
    V_ = psum32(V_); V_ = psum16(V_);

// ============ kernel 1: warmup + boundary records (no alpha stores) =========
__global__ __launch_bounds__(64, 1)
void hmm_m1(const float* __restrict__ obs,
            const float* __restrict__ tlog,
            const float* __restrict__ ilog,
            const float* __restrict__ emean,
            const float* __restrict__ elvar,
            float* __restrict__ wsf)
{
    MF_SETUP
    const int grp = (int)blockIdx.x & 31;
    const int c   = (int)blockIdx.x >> 5;        // chunk 0..63
    const int b   = grp * 16 + c16;              // this lane's chain
    const float* obl = obs + (size_t)b * TT;
    float* wrec = wsf + ((size_t)b * NCH + c) * RST;
    const int t0 = (c == 0) ? 0 : (c * CL - CW);

    float off = 0.f;
    float sc[8];
    bf16x8 Bf;
    const f32x4 Zc = {0.f, 0.f, 0.f, 0.f};
    float* ap = nullptr; (void)ap;               // unused (HEAVY_=false)
    float obuf[8];

    if (c == 0) {
        // exact init at t=0
        float il2v[8];
        {
            float m = ilog[0];
            #pragma unroll
            for (int k = 1; k < HH; ++k) m = fmaxf(m, ilog[k]);
            float z = 0.f;
            #pragma unroll
            for (int k = 0; k < HH; ++k) z += __expf(ilog[k] - m);
            float rz = 1.f / z;
            #pragma unroll
            for (int e = 0; e < 8; ++e)
                il2v[e] = __log2f(__expf(ilog[sig[e]] - m) * rz + F_EPS);
        }
        float o = obl[0];
        #pragma unroll
        for (int e = 0; e < 8; ++e) {
            float d = o - mean8[e];
            float a2 = il2v[e] + fmaf(d * d, -ec1v[e], ec0v[e]);
            sc[e] = __builtin_amdgcn_exp2f(a2);
        }
        PACK_SC_TO_BF
    } else {
        union { u32x4 u; bf16x8 h; } one_;
        one_.u[0] = 0x3F803F80u; one_.u[1] = 0x3F803F80u;
        one_.u[2] = 0x3F803F80u; one_.u[3] = 0x3F803F80u;
        Bf = one_.h;                              // uniform start
        #pragma unroll
        for (int e = 0; e < 8; ++e) sc[e] = 1.0f;
    }
    #pragma unroll
    for (int m = 1; m <= 8; ++m) obuf[m & 7] = obl[t0 + m];

    if (c > 0) {                                  // warmup CW steps
        for (int j = 0; j < CW / 8; ++j) { MGROUP8(t0 + 8 * j, false, false) }
        // record 1 at boundary t = c*CL: p, lambda_start, l2
        CHAIN_SUM(v)
        float l2 = __builtin_amdgcn_logf(v);
        if (g == 0) { wrec[32] = off + l2; wrec[34] = l2; }
        *(f4*)(wrec + 4 * g)      = (f4){sc[0], sc[1], sc[2], sc[3]};
        *(f4*)(wrec + 16 + 4 * g) = (f4){sc[4], sc[5], sc[6], sc[7]};
    }
    if (c < NCH - 1) {                            // traverse CL steps
        const int tW = c * CL;
        for (int j = 0; j < CL / 8; ++j) { MGROUP8(tW + 8 * j, false, false) }
        CHAIN_SUM(v)
        if (g == 0) wrec[33] = off + __builtin_amdgcn_logf(v);   // lambda_end
    }
}

// ============ kernel 3: corrected re-run, alpha stores, ll ==================
__global__ __launch_bounds__(64, 1)
void hmm_m3(const float* __restrict__ obs,
            const float* __restrict__ tlog,
            const float* __restrict__ ilog,
            const float* __restrict__ emean,
            const float* __restrict__ elvar,
            const float* __restrict__ wsf,
            float* __restrict__ alpha,
            float* __restrict__ ll)
{
    MF_SETUP
    const int grp = (int)blockIdx.x & 31;
    const int c   = (int)blockIdx.x >> 5;
    const int b   = grp * 16 + c16;
    const float* obl = obs + (size_t)b * TT;
    const size_t aBase = (size_t)b * TT * HH;
    const int tS = c * CL;

    float off;
    float sc[8];
    bf16x8 Bf;
    const f32x4 Zc = {0.f, 0.f, 0.f, 0.f};
    float obuf[8];
    float* ap = alpha + aBase + (size_t)(tS + 1) * HH;   // row base; lanes add 4g

    if (c == 0) {
        float il2v[8];
        {
            float m = ilog[0];
            #pragma unroll
            for (int k = 1; k < HH; ++k) m = fmaxf(m, ilog[k]);
            float z = 0.f;
            #pragma unroll
            for (int k = 0; k < HH; ++k) z += __expf(ilog[k] - m);
            float rz = 1.f / z;
            #pragma unroll
            for (int e = 0; e < 8; ++e)
                il2v[e] = __log2f(__expf(ilog[sig[e]] - m) * rz + F_EPS);
        }
        float o = obl[0];
        f32x4 w0, w1;
        #pragma unroll
        for (int e = 0; e < 8; ++e) {
            float d  = o - mean8[e];
            float a2 = il2v[e] + fmaf(d * d, -ec1v[e], ec0v[e]);
            sc[e] = __builtin_amdgcn_exp2f(a2);
            if (e < 4) w0[e] = a2 * F_LN2; else w1[e - 4] = a2 * F_LN2;
        }
        float* a0p = alpha + aBase;               // t = 0 row
        __builtin_nontemporal_store(w0, (f32x4*)(a0p + 4 * g));
        __builtin_nontemporal_store(w1, (f32x4*)(a0p + 16 + 4 * g));
        PACK_SC_TO_BF
        off = 0.f;
    } else {
        const float* wr = wsf + ((size_t)b * NCH + c) * RST;
        f4 r0 = *(const f4*)(wr + 4 * g);
        f4 r1 = *(const f4*)(wr + 16 + 4 * g);
        sc[0] = r0.x; sc[1] = r0.y; sc[2] = r0.z; sc[3] = r0.w;
        sc[4] = r1.x; sc[5] = r1.y; sc[6] = r1.z; sc[7] = r1.w;
        PACK_SC_TO_BF
        const float* wb = wsf + (size_t)b * NCH * RST;
        float T_ = wb[33];                        // true LSE2 at t = CL
        for (int cc = 1; cc < c; ++cc)
            T_ += wb[cc * RST + 33] - wb[cc * RST + 32];
        off = T_ - wr[34];                        // true(c*CL) - local l2
    }
    #pragma unroll
    for (int m = 1; m <= 8; ++m) obuf[m & 7] = obl[tS + m];

    if (c < NCH - 1) {
        for (int j = 0; j < CL / 8; ++j) { MGROUP8(tS + 8 * j, true, true) }
    } else {
        for (int j = 0; j < 7; ++j) { MGROUP8(tS + 8 * j, true, true) }
        // partial group: t = 4089..4095 (7 steps, no trailing renorm)
        MSTEP(1, tS + 56, true, false, true)
        MSTEP(2, tS + 56, true, false, true)
        MSTEP(3, tS + 56, true, false, true)
        MSTEP(4, tS + 56, true, false, true)
        MSTEP(5, tS + 56, true, false, true)
        MSTEP(6, tS + 56, true, false, true)
        MSTEP(7, tS + 56, true, false, true)
        // log-likelihood at t = 4095
        CHAIN_SUM(v)
        if (g == 0) ll[b] = (off + __builtin_amdgcn_logf(v)) * F_LN2;
    }
}

extern "C" void kernel_launch(void* const* d_in, const int* in_sizes, int n_in,
                              void* d_out, int out_size, void* d_ws, size_t ws_size,
                              hipStream_t stream)
{
    const float* obs = (const float*)d_in[0];
    const float* tl  = (const float*)d_in[1];
    const float* il  = (const float*)d_in[2];
    const float* em  = (const float*)d_in[3];
    const float* ev  = (const float*)d_in[4];
    float* alpha = (float*)d_out;
    float* ll    = alpha + (size_t)BB * TT * HH;
    float* wsf   = (float*)d_ws;   // needs BB*NCH*RST*4 = 4.72 MB

    hmm_m1<<<(BB / 16) * NCH, 64, 0, stream>>>(obs, tl, il, em, ev, wsf);
    hmm_m3<<<(BB / 16) * NCH, 64, 0, stream>>>(obs, tl, il, em, ev, wsf, alpha, ll);
}

// Round 19
// 94.821 us; speedup vs baseline: 1.2757x; 1.2757x over previous
//
#include <hip/hip_runtime.h>
#include <cmath>

#define HH 32
#define TT 4096
#define BB 512
#define NCH 64          // chunks per chain
#define CL  64          // chunk length (NCH*CL == TT)
#define CW  32          // warmup steps (multiple of 8; t0 stays 0 mod 8)
#define RST 36          // ws floats per (chain,chunk) record (144 B)

typedef float  f4     __attribute__((ext_vector_type(4)));
typedef float  f32x4  __attribute__((ext_vector_type(4)));
typedef short  bf16x8 __attribute__((ext_vector_type(8)));
typedef unsigned int u32x4 __attribute__((ext_vector_type(4)));

constexpr float F_EPS  = 1e-10f;
constexpr float F_MINV = 1e-6f;
constexpr float F_L2E  = 1.44269504088896340736f;   // log2(e)
constexpr float F_LN2  = 0.69314718055994530942f;   // ln(2)
constexpr float TWO_PI = 6.28318530717958647693f;

// ---- pair-combine with ^16/^32 partner (verified r8-r16): same value into
// both operands -> {own, partner} in some order -> sum/max unconditional.
#if __has_builtin(__builtin_amdgcn_permlane16_swap)
__device__ __forceinline__ float psum16(float a) {
    auto rr = __builtin_amdgcn_permlane16_swap(__float_as_uint(a), __float_as_uint(a), false, false);
    return __uint_as_float(rr[0]) + __uint_as_float(rr[1]);
}
__device__ __forceinline__ float pmax16(float a) {
    auto rr = __builtin_amdgcn_permlane16_swap(__float_as_uint(a), __float_as_uint(a), false, false);
    return fmaxf(__uint_as_float(rr[0]), __uint_as_float(rr[1]));
}
#else
__device__ __forceinline__ float psum16(float a) {
    float x, y;
    asm volatile("v_mov_b32 %0, %2\n\tv_mov_b32 %1, %2\n\tv_permlane16_swap_b32 %0, %1"
                 : "=&v"(x), "=&v"(y) : "v"(a));
    return x + y;
}
__device__ __forceinline__ float pmax16(float a) {
    float x, y;
    asm volatile("v_mov_b32 %0, %2\n\tv_mov_b32 %1, %2\n\tv_permlane16_swap_b32 %0, %1"
                 : "=&v"(x), "=&v"(y) : "v"(a));
    return fmaxf(x, y);
}
#endif
#if __has_builtin(__builtin_amdgcn_permlane32_swap)
__device__ __forceinline__ float psum32(float a) {
    auto rr = __builtin_amdgcn_permlane32_swap(__float_as_uint(a), __float_as_uint(a), false, false);
    return __uint_as_float(rr[0]) + __uint_as_float(rr[1]);
}
__device__ __forceinline__ float pmax32(float a) {
    auto rr = __builtin_amdgcn_permlane32_swap(__float_as_uint(a), __float_as_uint(a), false, false);
    return fmaxf(__uint_as_float(rr[0]), __uint_as_float(rr[1]));
}
#else
__device__ __forceinline__ float psum32(float a) {
    float x, y;
    asm volatile("v_mov_b32 %0, %2\n\tv_mov_b32 %1, %2\n\tv_permlane32_swap_b32 %0, %1"
                 : "=&v"(x), "=&v"(y) : "v"(a));
    return x + y;
}
__device__ __forceinline__ float pmax32(float a) {
    float x, y;
    asm volatile("v_mov_b32 %0, %2\n\tv_mov_b32 %1, %2\n\tv_permlane32_swap_b32 %0, %1"
                 : "=&v"(x), "=&v"(y) : "v"(a));
    return fmaxf(x, y);
}
#endif

__device__ __forceinline__ unsigned short f2bf(float f) {   // RNE f32->bf16
    unsigned u = __float_as_uint(f);
    return (unsigned short)((u + 0x7FFFu + ((u >> 16) & 1u)) >> 16);
}
__device__ __forceinline__ unsigned cvtpk(float lo, float hi) {
    unsigned r;
    asm("v_cvt_pk_bf16_f32 %0, %1, %2" : "=v"(r) : "v"(lo), "v"(hi));
    return r;
}

// Per-lane setup (verified r13/r16). Lane l: chain-col c16=l&15, quarter g=l>>4.
// sig[e]=4g+(e&3)+16(e>>2) is both the D-fragment row set AND the B-operand
// k-slots (sigma folded into A' columns) -> D feeds B with zero shuffles.
#define MF_SETUP                                                                \
    __shared__ float sA[HH * HH];                                               \
    const int lane = threadIdx.x;                                               \
    const int c16  = lane & 15;                                                 \
    const int g    = lane >> 4;                                                 \
    if (lane < HH) {                                                            \
        float rw[HH];                                                           \
        _Pragma("unroll")                                                       \
        for (int k = 0; k < HH; ++k) rw[k] = tlog[lane * HH + k];               \
        float m = rw[0];                                                        \
        _Pragma("unroll")                                                       \
        for (int k = 1; k < HH; ++k) m = fmaxf(m, rw[k]);                       \
        float z = 0.f;                                                          \
        _Pragma("unroll")                                                       \
        for (int k = 0; k < HH; ++k) { rw[k] = __expf(rw[k] - m); z += rw[k]; } \
        float rz = 1.f / z;                                                     \
        _Pragma("unroll")                                                       \
        for (int k = 0; k < HH; ++k) sA[lane * HH + k] = fmaf(rw[k], rz, F_EPS);\
    }                                                                           \
    __syncthreads();                                                            \
    int sig[8];                                                                 \
    _Pragma("unroll")                                                           \
    for (int e = 0; e < 8; ++e) sig[e] = 4 * g + (e & 3) + 16 * (e >> 2);       \
    bf16x8 aHi, aLo;                                                            \
    _Pragma("unroll")                                                           \
    for (int e = 0; e < 8; ++e) {                                               \
        aHi[e] = (short)f2bf(sA[sig[e] * HH + c16]);                            \
        aLo[e] = (short)f2bf(sA[sig[e] * HH + 16 + c16]);                       \
    }                                                                           \
    float mean8[8], ec1v[8], ec0v[8];                                           \
    _Pragma("unroll")                                                           \
    for (int e = 0; e < 8; ++e) {                                               \
        const int st = sig[e];                                                  \
        mean8[e] = emean[st];                                                   \
        float var = __expf(elvar[st]) + F_MINV;                                 \
        ec1v[e] = 0.5f * F_L2E / var;                                           \
        ec0v[e] = -0.5f * __logf(TWO_PI * var) * F_L2E;                         \
    }

// One recurrence step at t = TB_+U_ (slot (TB_+U_)&7 == U_&7 since TB_%8==0).
#define MSTEP(U_, TB_, HEAVY_, RENORM_, CLAMP_)                                 \
    {                                                                           \
        const float o_ = obuf[(U_) & 7];                                        \
        float qv_[8], e2_[8];                                                   \
        _Pragma("unroll")                                                       \
        for (int e = 0; e < 8; ++e) {                                           \
            float d_ = o_ - mean8[e];                                           \
            qv_[e] = fmaf(d_ * d_, -ec1v[e], ec0v[e]);                          \
            e2_[e] = __builtin_amdgcn_exp2f(qv_[e]);                            \
        }                                                                       \
        f32x4 S0_ = __builtin_amdgcn_mfma_f32_16x16x32_bf16(aHi, Bf, Zc, 0,0,0);\
        f32x4 S1_ = __builtin_amdgcn_mfma_f32_16x16x32_bf16(aLo, Bf, Zc, 0,0,0);\
        sc[0] = S0_[0] * e2_[0]; sc[1] = S0_[1] * e2_[1];                       \
        sc[2] = S0_[2] * e2_[2]; sc[3] = S0_[3] * e2_[3];                       \
        sc[4] = S1_[0] * e2_[4]; sc[5] = S1_[1] * e2_[5];                       \
        sc[6] = S1_[2] * e2_[6]; sc[7] = S1_[3] * e2_[7];                       \
        if (HEAVY_) {                                                           \
            f32x4 v0_, v1_;                                                     \
            v0_[0] = (off + qv_[0] + __builtin_amdgcn_logf(S0_[0])) * F_LN2;    \
            v0_[1] = (off + qv_[1] + __builtin_amdgcn_logf(S0_[1])) * F_LN2;    \
            v0_[2] = (off + qv_[2] + __builtin_amdgcn_logf(S0_[2])) * F_LN2;    \
            v0_[3] = (off + qv_[3] + __builtin_amdgcn_logf(S0_[3])) * F_LN2;    \
            v1_[0] = (off + qv_[4] + __builtin_amdgcn_logf(S1_[0])) * F_LN2;    \
            v1_[1] = (off + qv_[5] + __builtin_amdgcn_logf(S1_[1])) * F_LN2;    \
            v1_[2] = (off + qv_[6] + __builtin_amdgcn_logf(S1_[2])) * F_LN2;    \
            v1_[3] = (off + qv_[7] + __builtin_amdgcn_logf(S1_[3])) * F_LN2;    \
            *(f32x4*)(ap + 4 * g)      = v0_;                                   \
            *(f32x4*)(ap + 16 + 4 * g) = v1_;                                   \
            ap += HH;                                                           \
        }                                                                       \
        if (RENORM_) {                                                          \
            float m_ = fmaxf(fmaxf(fmaxf(sc[0], sc[1]), fmaxf(sc[2], sc[3])),   \
                             fmaxf(fmaxf(sc[4], sc[5]), fmaxf(sc[6], sc[7])));  \
            m_ = pmax32(m_); m_ = pmax16(m_);                                   \
            int ee_; frexpf(m_, &ee_);                                          \
            float s_ = ldexpf(1.0f, -ee_);                                      \
            _Pragma("unroll")                                                   \
            for (int e = 0; e < 8; ++e) sc[e] *= s_;                            \
            off += (float)ee_;                                                  \
        }                                                                       \
        {                                                                       \
            union { u32x4 u; bf16x8 h; } cv_;                                   \
            cv_.u[0] = cvtpk(sc[0], sc[1]); cv_.u[1] = cvtpk(sc[2], sc[3]);     \
            cv_.u[2] = cvtpk(sc[4], sc[5]); cv_.u[3] = cvtpk(sc[6], sc[7]);     \
            Bf = cv_.h;                                                         \
        }                                                                       \
        {                                                                       \
            int tr_ = (TB_) + (U_) + 8;                                         \
            if (CLAMP_) tr_ = (tr_ > TT - 1) ? (TT - 1) : tr_;                  \
            obuf[(U_) & 7] = obl[tr_];                                          \
        }                                                                       \
    }

#define MGROUP8(TB_, HEAVY_, CLAMP_)                                            \
    MSTEP(1, TB_, HEAVY_, false, CLAMP_)                                        \
    MSTEP(2, TB_, HEAVY_, false, CLAMP_)                                        \
    MSTEP(3, TB_, HEAVY_, false, CLAMP_)                                        \
    MSTEP(4, TB_, HEAVY_, false, CLAMP_)                                        \
    MSTEP(5, TB_, HEAVY_, false, CLAMP_)                                        \
    MSTEP(6, TB_, HEAVY_, false, CLAMP_)                                        \
    MSTEP(7, TB_, HEAVY_, false, CLAMP_)                                        \
    MSTEP(8, TB_, HEAVY_, true,  CLAMP_)

#define PACK_SC_TO_BF                                                           \
    { union { u32x4 u; bf16x8 h; } cv_;                                         \
      cv_.u[0] = cvtpk(sc[0], sc[1]); cv_.u[1] = cvtpk(sc[2], sc[3]);           \
      cv_.u[2] = cvtpk(sc[4], sc[5]); cv_.u[3] = cvtpk(sc[6], sc[7]);           \
      Bf = cv_.h; }

#define CHAIN_SUM(V_)                                                           \
    float V_ = ((sc[0] + sc[1]) + (sc[2] + sc[3]))                              \
             + ((sc[4] + sc[5]) + (sc[6] + sc[7]));                             \
    V_ = psum32(V_); V_ = psum16(V_);

// ============ kernel 1: warmup + boundary records (no alpha stores) =========
__global__ __launch_bounds__(64, 1)
void hmm_m1(const float* __restrict__ obs,
            const float* __restrict__ tlog,
            const float* __restrict__ ilog,
            const float* __restrict__ emean,
            const float* __restrict__ elvar,
            float* __restrict__ wsf)
{
    MF_SETUP
    const int grp = (int)blockIdx.x & 31;
    const int c   = (int)blockIdx.x >> 5;        // chunk 0..63
    const int b   = grp * 16 + c16;              // this lane's chain
    const float* obl = obs + (size_t)b * TT;
    float* wrec = wsf + ((size_t)b * NCH + c) * RST;
    const int t0 = (c == 0) ? 0 : (c * CL - CW);

    float off = 0.f;
    float sc[8];
    bf16x8 Bf;
    const f32x4 Zc = {0.f, 0.f, 0.f, 0.f};
    float* ap = nullptr; (void)ap;               // unused (HEAVY_=false)
    float obuf[8];

    if (c == 0) {
        // exact init at t=0
        float il2v[8];
        {
            float m = ilog[0];
            #pragma unroll
            for (int k = 1; k < HH; ++k) m = fmaxf(m, ilog[k]);
            float z = 0.f;
            #pragma unroll
            for (int k = 0; k < HH; ++k) z += __expf(ilog[k] - m);
            float rz = 1.f / z;
            #pragma unroll
            for (int e = 0; e < 8; ++e)
                il2v[e] = __log2f(__expf(ilog[sig[e]] - m) * rz + F_EPS);
        }
        float o = obl[0];
        #pragma unroll
        for (int e = 0; e < 8; ++e) {
            float d = o - mean8[e];
            float a2 = il2v[e] + fmaf(d * d, -ec1v[e], ec0v[e]);
            sc[e] = __builtin_amdgcn_exp2f(a2);
        }
        PACK_SC_TO_BF
    } else {
        union { u32x4 u; bf16x8 h; } one_;
        one_.u[0] = 0x3F803F80u; one_.u[1] = 0x3F803F80u;
        one_.u[2] = 0x3F803F80u; one_.u[3] = 0x3F803F80u;
        Bf = one_.h;                              // uniform start
        #pragma unroll
        for (int e = 0; e < 8; ++e) sc[e] = 1.0f;
    }
    #pragma unroll
    for (int m = 1; m <= 8; ++m) obuf[m & 7] = obl[t0 + m];

    if (c > 0) {                                  // warmup CW steps
        for (int j = 0; j < CW / 8; ++j) { MGROUP8(t0 + 8 * j, false, false) }
        // record 1 at boundary t = c*CL: p, lambda_start, l2
        CHAIN_SUM(v)
        float l2 = __builtin_amdgcn_logf(v);
        if (g == 0) { wrec[32] = off + l2; wrec[34] = l2; }
        *(f4*)(wrec + 4 * g)      = (f4){sc[0], sc[1], sc[2], sc[3]};
        *(f4*)(wrec + 16 + 4 * g) = (f4){sc[4], sc[5], sc[6], sc[7]};
    }
    if (c < NCH - 1) {                            // traverse CL steps
        const int tW = c * CL;
        for (int j = 0; j < CL / 8; ++j) { MGROUP8(tW + 8 * j, false, false) }
        CHAIN_SUM(v)
        if (g == 0) wrec[33] = off + __builtin_amdgcn_logf(v);   // lambda_end
    }
}

// ============ kernel 3: corrected re-run, alpha stores, ll ==================
__global__ __launch_bounds__(64, 1)
void hmm_m3(const float* __restrict__ obs,
            const float* __restrict__ tlog,
            const float* __restrict__ ilog,
            const float* __restrict__ emean,
            const float* __restrict__ elvar,
            const float* __restrict__ wsf,
            float* __restrict__ alpha,
            float* __restrict__ ll)
{
    MF_SETUP
    const int grp = (int)blockIdx.x & 31;
    const int c   = (int)blockIdx.x >> 5;
    const int b   = grp * 16 + c16;
    const float* obl = obs + (size_t)b * TT;
    const size_t aBase = (size_t)b * TT * HH;
    const int tS = c * CL;

    float off;
    float sc[8];
    bf16x8 Bf;
    const f32x4 Zc = {0.f, 0.f, 0.f, 0.f};
    float obuf[8];
    float* ap = alpha + aBase + (size_t)(tS + 1) * HH;   // row base; lanes add 4g

    if (c == 0) {
        float il2v[8];
        {
            float m = ilog[0];
            #pragma unroll
            for (int k = 1; k < HH; ++k) m = fmaxf(m, ilog[k]);
            float z = 0.f;
            #pragma unroll
            for (int k = 0; k < HH; ++k) z += __expf(ilog[k] - m);
            float rz = 1.f / z;
            #pragma unroll
            for (int e = 0; e < 8; ++e)
                il2v[e] = __log2f(__expf(ilog[sig[e]] - m) * rz + F_EPS);
        }
        float o = obl[0];
        f32x4 w0, w1;
        #pragma unroll
        for (int e = 0; e < 8; ++e) {
            float d  = o - mean8[e];
            float a2 = il2v[e] + fmaf(d * d, -ec1v[e], ec0v[e]);
            sc[e] = __builtin_amdgcn_exp2f(a2);
            if (e < 4) w0[e] = a2 * F_LN2; else w1[e - 4] = a2 * F_LN2;
        }
        float* a0p = alpha + aBase;               // t = 0 row
        *(f32x4*)(a0p + 4 * g)      = w0;
        *(f32x4*)(a0p + 16 + 4 * g) = w1;
        PACK_SC_TO_BF
        off = 0.f;
    } else {
        const float* wr = wsf + ((size_t)b * NCH + c) * RST;
        f4 r0 = *(const f4*)(wr + 4 * g);
        f4 r1 = *(const f4*)(wr + 16 + 4 * g);
        sc[0] = r0.x; sc[1] = r0.y; sc[2] = r0.z; sc[3] = r0.w;
        sc[4] = r1.x; sc[5] = r1.y; sc[6] = r1.z; sc[7] = r1.w;
        PACK_SC_TO_BF
        const float* wb = wsf + (size_t)b * NCH * RST;
        float T_ = wb[33];                        // true LSE2 at t = CL
        for (int cc = 1; cc < c; ++cc)
            T_ += wb[cc * RST + 33] - wb[cc * RST + 32];
        off = T_ - wr[34];                        // true(c*CL) - local l2
    }
    #pragma unroll
    for (int m = 1; m <= 8; ++m) obuf[m & 7] = obl[tS + m];

    if (c < NCH - 1) {
        for (int j = 0; j < CL / 8; ++j) { MGROUP8(tS + 8 * j, true, true) }
    } else {
        for (int j = 0; j < 7; ++j) { MGROUP8(tS + 8 * j, true, true) }
        // partial group: t = 4089..4095 (7 steps, no trailing renorm)
        MSTEP(1, tS + 56, true, false, true)
        MSTEP(2, tS + 56, true, false, true)
        MSTEP(3, tS + 56, true, false, true)
        MSTEP(4, tS + 56, true, false, true)
        MSTEP(5, tS + 56, true, false, true)
        MSTEP(6, tS + 56, true, false, true)
        MSTEP(7, tS + 56, true, false, true)
        // log-likelihood at t = 4095
        CHAIN_SUM(v)
        if (g == 0) ll[b] = (off + __builtin_amdgcn_logf(v)) * F_LN2;
    }
}

extern "C" void kernel_launch(void* const* d_in, const int* in_sizes, int n_in,
                              void* d_out, int out_size, void* d_ws, size_t ws_size,
                              hipStream_t stream)
{
    const float* obs = (const float*)d_in[0];
    const float* tl  = (const float*)d_in[1];
    const float* il  = (const float*)d_in[2];
    const float* em  = (const float*)d_in[3];
    const float* ev  = (const float*)d_in[4];
    float* alpha = (float*)d_out;
    float* ll    = alpha + (size_t)BB * TT * HH;
    float* wsf   = (float*)d_ws;   // needs BB*NCH*RST*4 = 4.72 MB

    hmm_m1<<<(BB / 16) * NCH, 64, 0, stream>>>(obs, tl, il, em, ev, wsf);
    hmm_m3<<<(BB / 16) * NCH, 64, 0, stream>>>(obs, tl, il, em, ev, wsf, alpha, ll);
}